// Round 4
// baseline (79.211 us; speedup 1.0000x reference)
//
#include <hip/hip_runtime.h>
#include <math.h>

#define MARGIN 1.0f
#define NI 16   // i's per pair-kernel block (register-blocked, wave-uniform)

// ---------------- Kernel A: per-row distance + ticket init ----------------
__global__ __launch_bounds__(256) void dist_kernel(
    const float* __restrict__ pv,   // (B, P)
    const float* __restrict__ pt,   // (P,)
    float* __restrict__ dist,       // (B,)
    unsigned* __restrict__ ticket,
    int B, int P)
{
    int i = blockIdx.x * 256 + threadIdx.x;
    if (i == 0) *ticket = 0u;       // workspace is poisoned each iteration
    if (i >= B) return;
    const float* row = pv + (size_t)i * P;
    float s = 0.f;
    if (P == 16) {
        const float4* r4 = (const float4*)row;
        const float4* t4 = (const float4*)pt;
        #pragma unroll
        for (int q = 0; q < 4; ++q) {
            float4 r = r4[q], t = t4[q];
            float d0 = r.x - t.x; s = fmaf(d0, d0, s);
            float d1 = r.y - t.y; s = fmaf(d1, d1, s);
            float d2 = r.z - t.z; s = fmaf(d2, d2, s);
            float d3 = r.w - t.w; s = fmaf(d3, d3, s);
        }
    } else {
        for (int p = 0; p < P; ++p) { float d = row[p] - pt[p]; s = fmaf(d, d, s); }
    }
    dist[i] = sqrtf(s);
}

// ---------------- Kernel B: all-pairs masked loss + last-block finalize ----------------
// Hot loop identical to round 3 (pure VALU, no LDS, no atomics). Finalize is fused
// via the standard last-block-done pattern: plain partial stores, ONE u32 ticket
// atomic per block, last block reduces. (Round-1's cost was the per-block fp64
// same-line atomic adds -- those are gone.)
__global__ __launch_bounds__(256) void pair_fin_kernel(
    const float* __restrict__ e,     // (B,)
    const float* __restrict__ dist,  // (B,)
    float* __restrict__ psum,        // (nblk,)
    float* __restrict__ pcnt,        // (nblk,)
    unsigned* __restrict__ ticket,
    float* __restrict__ out,
    int B, int nblk)
{
    const int tid = threadIdx.x;
    const int i0 = blockIdx.x * NI;

    float di[NI], ai[NI];
    #pragma unroll
    for (int ii = 0; ii < NI; ++ii) {
        const int i = i0 + ii;
        const bool iok = i < B;
        di[ii] = iok ? dist[i] : INFINITY;        // +inf: mask never true
        ai[ii] = iok ? (e[i] + MARGIN) : 0.f;
    }

    // 4 independent sum chains + 4 count chains (counts exact)
    float s0 = 0.f, s1 = 0.f, s2 = 0.f, s3 = 0.f;
    unsigned c0 = 0u, c1 = 0u, c2 = 0u, c3 = 0u;

    auto proc = [&](float dj, float ej) {
        #pragma unroll
        for (int ii = 0; ii < NI; ii += 4) {
            { const bool m = di[ii]   < dj; const float t = fmaxf(ai[ii]   - ej, 0.f); s0 += m ? t : 0.f; c0 += (unsigned)m; }
            { const bool m = di[ii+1] < dj; const float t = fmaxf(ai[ii+1] - ej, 0.f); s1 += m ? t : 0.f; c1 += (unsigned)m; }
            { const bool m = di[ii+2] < dj; const float t = fmaxf(ai[ii+2] - ej, 0.f); s2 += m ? t : 0.f; c2 += (unsigned)m; }
            { const bool m = di[ii+3] < dj; const float t = fmaxf(ai[ii+3] - ej, 0.f); s3 += m ? t : 0.f; c3 += (unsigned)m; }
        }
    };

    const int nvec = B >> 2;
    const float4* d4 = (const float4*)dist;
    const float4* e4 = (const float4*)e;

    // full rounds (all 256 threads in-bounds), one-iteration manual prefetch
    const int nfull = nvec >> 8;                 // 8 for B=8192
    float4 dc, ec;
    if (nfull > 0) { dc = d4[tid]; ec = e4[tid]; }
    for (int s = 0; s < nfull; ++s) {
        float4 dn, en;
        const bool more = (s + 1) < nfull;
        const int jn = ((s + 1) << 8) + tid;
        if (more) { dn = d4[jn]; en = e4[jn]; }
        proc(dc.x, ec.x);
        proc(dc.y, ec.y);
        proc(dc.z, ec.z);
        proc(dc.w, ec.w);
        if (more) { dc = dn; ec = en; }
    }
    // vector remainder (general B)
    for (int j4 = (nfull << 8) + tid; j4 < nvec; j4 += 256) {
        const float4 dv = d4[j4], ev = e4[j4];
        proc(dv.x, ev.x); proc(dv.y, ev.y); proc(dv.z, ev.z); proc(dv.w, ev.w);
    }
    // scalar remainder (general B)
    for (int j = (nvec << 2) + tid; j < B; j += 256) {
        proc(dist[j], e[j]);
    }

    // wave reduce, then tiny cross-wave reduce
    float sum = (s0 + s1) + (s2 + s3);
    float cnt = (float)((c0 + c1) + (c2 + c3));
    #pragma unroll
    for (int o = 32; o > 0; o >>= 1) {
        sum += __shfl_xor(sum, o);
        cnt += __shfl_xor(cnt, o);
    }

    __shared__ float rs[4], rc[4];
    __shared__ unsigned lastflag;
    const int wid = tid >> 6;
    if ((tid & 63) == 0) { rs[wid] = sum; rc[wid] = cnt; }
    __syncthreads();
    if (tid == 0) {
        psum[blockIdx.x] = (rs[0] + rs[1]) + (rs[2] + rs[3]);
        pcnt[blockIdx.x] = (rc[0] + rc[1]) + (rc[2] + rc[3]);
        __threadfence();                          // release partials
        unsigned t = atomicAdd(ticket, 1u);       // device-scope, total order
        lastflag = (t == (unsigned)(nblk - 1)) ? 1u : 0u;
    }
    __syncthreads();

    if (lastflag) {
        __threadfence();                          // acquire: see all partials
        __shared__ double ss[256];
        __shared__ double sc[256];
        double s = 0.0, c = 0.0;
        for (int k = tid; k < nblk; k += 256) {
            s += (double)psum[k];
            c += (double)pcnt[k];
        }
        ss[tid] = s;
        sc[tid] = c;
        __syncthreads();
        for (int st = 128; st > 0; st >>= 1) {
            if (tid < st) {
                ss[tid] += ss[tid + st];
                sc[tid] += sc[tid + st];
            }
            __syncthreads();
        }
        if (tid == 0) {
            double cn = sc[0] < 1.0 ? 1.0 : sc[0];
            out[0] = (float)(ss[0] / cn);
        }
    }
}

extern "C" void kernel_launch(void* const* d_in, const int* in_sizes, int n_in,
                              void* d_out, int out_size, void* d_ws, size_t ws_size,
                              hipStream_t stream)
{
    const float* energies = (const float*)d_in[0];  // (B,1) flat = B floats
    const float* pv       = (const float*)d_in[1];  // (B,P)
    const float* pt       = (const float*)d_in[2];  // (P,)
    int B = in_sizes[0];
    int P = in_sizes[2];

    int nblk = (B + NI - 1) / NI;    // 512 for B=8192 -> exactly 2 blocks/CU

    float* dist       = (float*)d_ws;        // B floats
    float* psum       = dist + B;            // nblk floats
    float* pcnt       = psum + nblk;         // nblk floats
    unsigned* ticket  = (unsigned*)(pcnt + nblk);

    dist_kernel<<<(B + 255) / 256, 256, 0, stream>>>(pv, pt, dist, ticket, B, P);
    pair_fin_kernel<<<nblk, 256, 0, stream>>>(energies, dist, psum, pcnt, ticket,
                                              (float*)d_out, B, nblk);
}

// Round 5
// 76.151 us; speedup vs baseline: 1.0402x; 1.0402x over previous
//
#include <hip/hip_runtime.h>
#include <math.h>

#define MARGIN 1.0f
#define NI 32    // i's per block (register-blocked)
#define BT 512   // threads per block -> 256 blocks at B=8192, exactly 1/CU

// ---------------- Kernel A: fused distance + all-pairs masked loss ----------------
// Each block owns NI i's. dj is recomputed on the fly from pv (L2-resident, 512 KB);
// arithmetic chain is bit-identical to the old dist kernel (same fmaf order + sqrtf),
// so results match exactly. No atomics, no fences, no device-scope sync.
__global__ __launch_bounds__(BT) void pairdist_kernel(
    const float* __restrict__ e,    // (B,)
    const float* __restrict__ pv,   // (B, P)
    const float* __restrict__ pt,   // (P,)
    float* __restrict__ psum,       // (nblk,)
    float* __restrict__ pcnt,       // (nblk,)
    int B, int P)
{
    const int tid = threadIdx.x;
    const int i0  = blockIdx.x * NI;

    // i-side: NI rows' distances + biased energies, computed by NI lanes, shared
    __shared__ float sdi[NI], sai[NI];
    if (tid < NI) {
        const int i = i0 + tid;
        float dv = INFINITY, av = 0.f;   // +inf: mask never true for padded i
        if (i < B) {
            const float* row = pv + (size_t)i * P;
            float s = 0.f;
            if (P == 16) {
                const float4* r4 = (const float4*)row;
                const float4* t4 = (const float4*)pt;
                #pragma unroll
                for (int q = 0; q < 4; ++q) {
                    float4 r = r4[q], t = t4[q];
                    float d0 = r.x - t.x; s = fmaf(d0, d0, s);
                    float d1 = r.y - t.y; s = fmaf(d1, d1, s);
                    float d2 = r.z - t.z; s = fmaf(d2, d2, s);
                    float d3 = r.w - t.w; s = fmaf(d3, d3, s);
                }
            } else {
                for (int p = 0; p < P; ++p) { float d = row[p] - pt[p]; s = fmaf(d, d, s); }
            }
            dv = sqrtf(s);
            av = e[i] + MARGIN;
        }
        sdi[tid] = dv; sai[tid] = av;
    }
    __syncthreads();

    float di[NI], ai[NI];
    #pragma unroll
    for (int ii = 0; ii < NI; ++ii) { di[ii] = sdi[ii]; ai[ii] = sai[ii]; }  // broadcast

    // 4 independent sum chains + 4 count chains (counts exact: block total <= 2^18)
    float s0 = 0.f, s1 = 0.f, s2 = 0.f, s3 = 0.f;
    unsigned c0 = 0u, c1 = 0u, c2 = 0u, c3 = 0u;

    auto proc = [&](float dj, float ej) {
        #pragma unroll
        for (int ii = 0; ii < NI; ii += 4) {
            { const bool m = di[ii]   < dj; const float t = fmaxf(ai[ii]   - ej, 0.f); s0 += m ? t : 0.f; c0 += (unsigned)m; }
            { const bool m = di[ii+1] < dj; const float t = fmaxf(ai[ii+1] - ej, 0.f); s1 += m ? t : 0.f; c1 += (unsigned)m; }
            { const bool m = di[ii+2] < dj; const float t = fmaxf(ai[ii+2] - ej, 0.f); s2 += m ? t : 0.f; c2 += (unsigned)m; }
            { const bool m = di[ii+3] < dj; const float t = fmaxf(ai[ii+3] - ej, 0.f); s3 += m ? t : 0.f; c3 += (unsigned)m; }
        }
    };

    if (P == 16) {
        const float4 t0 = ((const float4*)pt)[0];
        const float4 t1 = ((const float4*)pt)[1];
        const float4 t2 = ((const float4*)pt)[2];
        const float4 t3 = ((const float4*)pt)[3];

        auto dist_of = [&](float4 r0, float4 r1, float4 r2, float4 r3) {
            float s = 0.f, d;
            d = r0.x - t0.x; s = fmaf(d, d, s);
            d = r0.y - t0.y; s = fmaf(d, d, s);
            d = r0.z - t0.z; s = fmaf(d, d, s);
            d = r0.w - t0.w; s = fmaf(d, d, s);
            d = r1.x - t1.x; s = fmaf(d, d, s);
            d = r1.y - t1.y; s = fmaf(d, d, s);
            d = r1.z - t1.z; s = fmaf(d, d, s);
            d = r1.w - t1.w; s = fmaf(d, d, s);
            d = r2.x - t2.x; s = fmaf(d, d, s);
            d = r2.y - t2.y; s = fmaf(d, d, s);
            d = r2.z - t2.z; s = fmaf(d, d, s);
            d = r2.w - t2.w; s = fmaf(d, d, s);
            d = r3.x - t3.x; s = fmaf(d, d, s);
            d = r3.y - t3.y; s = fmaf(d, d, s);
            d = r3.z - t3.z; s = fmaf(d, d, s);
            d = r3.w - t3.w; s = fmaf(d, d, s);
            return sqrtf(s);
        };

        const int nfull = B / BT;   // rounds with all threads in-bounds
        float4 r0, r1, r2, r3; float ejc;
        if (nfull > 0) {
            const float4* row = (const float4*)(pv + (size_t)tid * 16);
            r0 = row[0]; r1 = row[1]; r2 = row[2]; r3 = row[3];
            ejc = e[tid];
        }
        for (int s = 0; s < nfull; ++s) {
            float4 n0, n1, n2, n3; float ejn;
            const bool more = (s + 1) < nfull;
            if (more) {
                const int jn = (s + 1) * BT + tid;
                const float4* row = (const float4*)(pv + (size_t)jn * 16);
                n0 = row[0]; n1 = row[1]; n2 = row[2]; n3 = row[3];
                ejn = e[jn];
            }
            proc(dist_of(r0, r1, r2, r3), ejc);
            if (more) { r0 = n0; r1 = n1; r2 = n2; r3 = n3; ejc = ejn; }
        }
        // remainder (general B)
        for (int j = nfull * BT + tid; j < B; j += BT) {
            const float4* row = (const float4*)(pv + (size_t)j * 16);
            proc(dist_of(row[0], row[1], row[2], row[3]), e[j]);
        }
    } else {
        for (int j = tid; j < B; j += BT) {
            const float* row = pv + (size_t)j * P;
            float s = 0.f;
            for (int p = 0; p < P; ++p) { float d = row[p] - pt[p]; s = fmaf(d, d, s); }
            proc(sqrtf(s), e[j]);
        }
    }

    // wave reduce, then tiny cross-wave reduce
    float sum = (s0 + s1) + (s2 + s3);
    float cnt = (float)((c0 + c1) + (c2 + c3));
    #pragma unroll
    for (int o = 32; o > 0; o >>= 1) {
        sum += __shfl_xor(sum, o);
        cnt += __shfl_xor(cnt, o);
    }

    __shared__ float rs[BT / 64], rc[BT / 64];
    const int wid = tid >> 6;
    if ((tid & 63) == 0) { rs[wid] = sum; rc[wid] = cnt; }
    __syncthreads();
    if (tid == 0) {
        float S = 0.f, C = 0.f;
        #pragma unroll
        for (int w = 0; w < BT / 64; ++w) { S += rs[w]; C += rc[w]; }
        psum[blockIdx.x] = S;
        pcnt[blockIdx.x] = C;
    }
}

// ---------------- Kernel B: final reduce + divide ----------------
__global__ __launch_bounds__(256) void finalize_kernel(
    const float* __restrict__ psum,
    const float* __restrict__ pcnt,
    float* __restrict__ out,
    int nblk)
{
    __shared__ double ss[256];
    __shared__ double sc[256];
    double s = 0.0, c = 0.0;
    for (int k = threadIdx.x; k < nblk; k += 256) {
        s += (double)psum[k];
        c += (double)pcnt[k];
    }
    ss[threadIdx.x] = s;
    sc[threadIdx.x] = c;
    __syncthreads();
    for (int st = 128; st > 0; st >>= 1) {
        if ((int)threadIdx.x < st) {
            ss[threadIdx.x] += ss[threadIdx.x + st];
            sc[threadIdx.x] += sc[threadIdx.x + st];
        }
        __syncthreads();
    }
    if (threadIdx.x == 0) {
        double cnt = sc[0] < 1.0 ? 1.0 : sc[0];
        out[0] = (float)(ss[0] / cnt);
    }
}

extern "C" void kernel_launch(void* const* d_in, const int* in_sizes, int n_in,
                              void* d_out, int out_size, void* d_ws, size_t ws_size,
                              hipStream_t stream)
{
    const float* energies = (const float*)d_in[0];  // (B,1) flat = B floats
    const float* pv       = (const float*)d_in[1];  // (B,P)
    const float* pt       = (const float*)d_in[2];  // (P,)
    int B = in_sizes[0];
    int P = in_sizes[2];

    int nblk = (B + NI - 1) / NI;    // 256 for B=8192 -> exactly 1 block/CU

    float* psum = (float*)d_ws;      // nblk floats
    float* pcnt = psum + nblk;       // nblk floats

    pairdist_kernel<<<nblk, BT, 0, stream>>>(energies, pv, pt, psum, pcnt, B, P);
    finalize_kernel<<<1, 256, 0, stream>>>(psum, pcnt, (float*)d_out, nblk);
}

// Round 6
// 71.637 us; speedup vs baseline: 1.1057x; 1.0630x over previous
//
#include <hip/hip_runtime.h>
#include <math.h>

#define MARGIN 1.0f
#define NI 16   // i's per pair-kernel block (register-blocked, wave-uniform)

// ---------------- Kernel A: per-row distance ----------------
__global__ __launch_bounds__(256) void dist_kernel(
    const float* __restrict__ pv,   // (B, P)
    const float* __restrict__ pt,   // (P,)
    float* __restrict__ dist,       // (B,)
    int B, int P)
{
    int i = blockIdx.x * 256 + threadIdx.x;
    if (i >= B) return;
    const float* row = pv + (size_t)i * P;
    float s = 0.f;
    if (P == 16) {
        const float4* r4 = (const float4*)row;
        const float4* t4 = (const float4*)pt;
        #pragma unroll
        for (int q = 0; q < 4; ++q) {
            float4 r = r4[q], t = t4[q];
            float d0 = r.x - t.x; s = fmaf(d0, d0, s);
            float d1 = r.y - t.y; s = fmaf(d1, d1, s);
            float d2 = r.z - t.z; s = fmaf(d2, d2, s);
            float d3 = r.w - t.w; s = fmaf(d3, d3, s);
        }
    } else {
        for (int p = 0; p < P; ++p) { float d = row[p] - pt[p]; s = fmaf(d, d, s); }
    }
    dist[i] = sqrtf(s);
}

// ---------------- Kernel B: all-pairs masked loss ----------------
// Per block: NI i's in registers (wave-uniform scalar loads). Each thread walks
// coalesced float4 j's straight from global (arrays are 32 KB each -> L2-resident).
// Hot loop is pure VALU (6 ops/pair), no LDS, no atomics. Measured best structure
// (R3 = 71.2 us); both fusion variants (ticket finalize, dist recompute) regressed.
__global__ __launch_bounds__(256) void pair_kernel(
    const float* __restrict__ e,     // (B,)
    const float* __restrict__ dist,  // (B,)
    float* __restrict__ psum,        // (nblk,)
    float* __restrict__ pcnt,        // (nblk,)
    int B)
{
    const int tid = threadIdx.x;
    const int i0 = blockIdx.x * NI;

    float di[NI], ai[NI];
    #pragma unroll
    for (int ii = 0; ii < NI; ++ii) {
        const int i = i0 + ii;
        const bool iok = i < B;
        di[ii] = iok ? dist[i] : INFINITY;        // +inf: mask never true
        ai[ii] = iok ? (e[i] + MARGIN) : 0.f;
    }

    // 4 independent sum chains + 4 count chains (counts exact)
    float s0 = 0.f, s1 = 0.f, s2 = 0.f, s3 = 0.f;
    unsigned c0 = 0u, c1 = 0u, c2 = 0u, c3 = 0u;

    auto proc = [&](float dj, float ej) {
        #pragma unroll
        for (int ii = 0; ii < NI; ii += 4) {
            { const bool m = di[ii]   < dj; const float t = fmaxf(ai[ii]   - ej, 0.f); s0 += m ? t : 0.f; c0 += (unsigned)m; }
            { const bool m = di[ii+1] < dj; const float t = fmaxf(ai[ii+1] - ej, 0.f); s1 += m ? t : 0.f; c1 += (unsigned)m; }
            { const bool m = di[ii+2] < dj; const float t = fmaxf(ai[ii+2] - ej, 0.f); s2 += m ? t : 0.f; c2 += (unsigned)m; }
            { const bool m = di[ii+3] < dj; const float t = fmaxf(ai[ii+3] - ej, 0.f); s3 += m ? t : 0.f; c3 += (unsigned)m; }
        }
    };

    const int nvec = B >> 2;
    const float4* d4 = (const float4*)dist;
    const float4* e4 = (const float4*)e;

    // full rounds (all 256 threads in-bounds), one-iteration manual prefetch
    const int nfull = nvec >> 8;                 // 8 for B=8192
    float4 dc, ec;
    if (nfull > 0) { dc = d4[tid]; ec = e4[tid]; }
    for (int s = 0; s < nfull; ++s) {
        float4 dn, en;
        const bool more = (s + 1) < nfull;
        const int jn = ((s + 1) << 8) + tid;
        if (more) { dn = d4[jn]; en = e4[jn]; }
        proc(dc.x, ec.x);
        proc(dc.y, ec.y);
        proc(dc.z, ec.z);
        proc(dc.w, ec.w);
        if (more) { dc = dn; ec = en; }
    }
    // vector remainder (general B)
    for (int j4 = (nfull << 8) + tid; j4 < nvec; j4 += 256) {
        const float4 dv = d4[j4], ev = e4[j4];
        proc(dv.x, ev.x); proc(dv.y, ev.y); proc(dv.z, ev.z); proc(dv.w, ev.w);
    }
    // scalar remainder (general B)
    for (int j = (nvec << 2) + tid; j < B; j += 256) {
        proc(dist[j], e[j]);
    }

    // wave reduce, then tiny cross-wave reduce
    float sum = (s0 + s1) + (s2 + s3);
    float cnt = (float)((c0 + c1) + (c2 + c3));
    #pragma unroll
    for (int o = 32; o > 0; o >>= 1) {
        sum += __shfl_xor(sum, o);
        cnt += __shfl_xor(cnt, o);
    }

    __shared__ float rs[4], rc[4];
    const int wid = tid >> 6;
    if ((tid & 63) == 0) { rs[wid] = sum; rc[wid] = cnt; }
    __syncthreads();
    if (tid == 0) {
        psum[blockIdx.x] = (rs[0] + rs[1]) + (rs[2] + rs[3]);
        pcnt[blockIdx.x] = (rc[0] + rc[1]) + (rc[2] + rc[3]);
    }
}

// ---------------- Kernel C: final reduce + divide ----------------
__global__ __launch_bounds__(256) void finalize_kernel(
    const float* __restrict__ psum,
    const float* __restrict__ pcnt,
    float* __restrict__ out,
    int nblk)
{
    __shared__ double ss[256];
    __shared__ double sc[256];
    double s = 0.0, c = 0.0;

    const int nv = nblk >> 2;                 // float4 partial loads
    const float4* p4 = (const float4*)psum;
    const float4* c4 = (const float4*)pcnt;
    for (int k = threadIdx.x; k < nv; k += 256) {
        const float4 a = p4[k], b = c4[k];
        s += (double)a.x + (double)a.y + (double)a.z + (double)a.w;
        c += (double)b.x + (double)b.y + (double)b.z + (double)b.w;
    }
    for (int k = (nv << 2) + threadIdx.x; k < nblk; k += 256) {
        s += (double)psum[k];
        c += (double)pcnt[k];
    }

    ss[threadIdx.x] = s;
    sc[threadIdx.x] = c;
    __syncthreads();
    for (int st = 128; st > 0; st >>= 1) {
        if ((int)threadIdx.x < st) {
            ss[threadIdx.x] += ss[threadIdx.x + st];
            sc[threadIdx.x] += sc[threadIdx.x + st];
        }
        __syncthreads();
    }
    if (threadIdx.x == 0) {
        double cnt = sc[0] < 1.0 ? 1.0 : sc[0];
        out[0] = (float)(ss[0] / cnt);
    }
}

extern "C" void kernel_launch(void* const* d_in, const int* in_sizes, int n_in,
                              void* d_out, int out_size, void* d_ws, size_t ws_size,
                              hipStream_t stream)
{
    const float* energies = (const float*)d_in[0];  // (B,1) flat = B floats
    const float* pv       = (const float*)d_in[1];  // (B,P)
    const float* pt       = (const float*)d_in[2];  // (P,)
    int B = in_sizes[0];
    int P = in_sizes[2];

    int nblk = (B + NI - 1) / NI;    // 512 for B=8192 -> exactly 2 blocks/CU

    float* dist = (float*)d_ws;      // B floats
    float* psum = dist + B;          // nblk floats
    float* pcnt = psum + nblk;       // nblk floats

    dist_kernel<<<(B + 255) / 256, 256, 0, stream>>>(pv, pt, dist, B, P);
    pair_kernel<<<nblk, 256, 0, stream>>>(energies, dist, psum, pcnt, B);
    finalize_kernel<<<1, 256, 0, stream>>>(psum, pcnt, (float*)d_out, nblk);
}